// Round 4
// baseline (357.457 us; speedup 1.0000x reference)
//
#include <hip/hip_runtime.h>
#include <math.h>

#define N_NODES 20000
#define N_EDGESC 320000
#define ET (N_EDGESC + N_NODES)   // 340000 incl. self-loops
#define F_IN 128
#define H1 512
#define H2 256
#define N_CLS 40
#define NEG_SLOPE 0.2f

typedef __attribute__((ext_vector_type(8))) short short8;
typedef __attribute__((ext_vector_type(4))) float floatx4;

__device__ __forceinline__ unsigned short f2bf(float x) {
    unsigned u = __float_as_uint(x);
    unsigned r = (u + 0x7fffu + ((u >> 16) & 1u)) >> 16;  // RNE
    return (unsigned short)r;
}
__device__ __forceinline__ float bflo(unsigned v) { return __uint_as_float(v << 16); }
__device__ __forceinline__ float bfhi(unsigned v) { return __uint_as_float(v & 0xffff0000u); }
__device__ __forceinline__ float leaky(float e) { return (e > 0.f) ? e : e * NEG_SLOPE; }

// async global->LDS, 16B per lane; lds dest = wave-uniform base + lane*16
__device__ __forceinline__ void async16(const unsigned short* g, unsigned short* l) {
    __builtin_amdgcn_global_load_lds(
        (const __attribute__((address_space(1))) unsigned int*)g,
        (__attribute__((address_space(3))) unsigned int*)l, 16, 0, 0);
}

// ---------------- CSR build ----------------

__global__ void zero_kernel(int* __restrict__ deg, float* __restrict__ alph) {
    int i = blockIdx.x * blockDim.x + threadIdx.x;
    if (i < N_NODES) deg[i] = 0;
    if (i < 6 * N_NODES) alph[i] = 0.f;
}

__global__ void count_deg_kernel(const int* __restrict__ ei, int* __restrict__ deg) {
    int e = blockIdx.x * blockDim.x + threadIdx.x;
    if (e >= ET) return;
    int d = (e < N_EDGESC) ? ei[N_EDGESC + e] : (e - N_EDGESC);
    atomicAdd(&deg[d], 1);
}

__global__ __launch_bounds__(1024) void scan_kernel(const int* __restrict__ deg,
                                                    int* __restrict__ rowptr,
                                                    int* __restrict__ writeptr) {
    __shared__ int sums[1024];
    int t = threadIdx.x;
    const int per = (N_NODES + 1023) / 1024;  // 20
    int base = t * per;
    int local = 0;
    for (int i = 0; i < per; ++i) {
        int idx = base + i;
        if (idx < N_NODES) local += deg[idx];
    }
    sums[t] = local;
    __syncthreads();
    for (int off = 1; off < 1024; off <<= 1) {
        int add = (t >= off) ? sums[t - off] : 0;
        __syncthreads();
        sums[t] += add;
        __syncthreads();
    }
    int run = sums[t] - local;
    for (int i = 0; i < per; ++i) {
        int idx = base + i;
        if (idx < N_NODES) {
            rowptr[idx] = run;
            writeptr[idx] = run;
            run += deg[idx];
        }
    }
    if (t == 1023) rowptr[N_NODES] = sums[1023];
}

__global__ void fill_kernel(const int* __restrict__ ei, int* __restrict__ writeptr,
                            int* __restrict__ csr_src) {
    int e = blockIdx.x * blockDim.x + threadIdx.x;
    if (e >= ET) return;
    int s, d;
    if (e < N_EDGESC) { s = ei[e]; d = ei[N_EDGESC + e]; }
    else { s = d = e - N_EDGESC; }
    int pos = atomicAdd(&writeptr[d], 1);
    csr_src[pos] = s;
}

// ---------------- casts ----------------

__global__ void cast_bf16_kernel(const float* __restrict__ in, unsigned short* __restrict__ out, int n) {
    int i = blockIdx.x * blockDim.x + threadIdx.x;
    if (i < n) out[i] = f2bf(in[i]);
}

__global__ void castT_kernel(const float* __restrict__ W, unsigned short* __restrict__ Wt,
                             int K, int N) {
    int i = blockIdx.x * blockDim.x + threadIdx.x;
    if (i >= K * N) return;
    int k = i / N, n = i - k * N;
    Wt[n * K + k] = f2bf(W[i]);
}

// ---------------- MFMA GEMM, 128x128 tile, BK=32, global_load_lds staging ----
// C(MxN) = A(MxK bf16 rm) * Bt(NxK bf16 rm). Fused per-row alpha dots:
// als[row] += sum_col C[row,col]*a_s[col] (fp32 acc), via quad-shuffle + atomic.
template <bool OUT_BF16>
__global__ __launch_bounds__(256) void gemm_mfma(const unsigned short* __restrict__ A,
                                                 const unsigned short* __restrict__ Bt,
                                                 void* __restrict__ Cp,
                                                 const float* __restrict__ a_s,
                                                 const float* __restrict__ a_d,
                                                 float* __restrict__ als,
                                                 float* __restrict__ ald,
                                                 int M, int K, int N) {
    __shared__ unsigned short As[128 * 32];  // [row][k], stride 32, no pad (async reqt)
    __shared__ unsigned short Bs[128 * 32];
    int t = threadIdx.x;
    int w = t >> 6, lane = t & 63;
    int quad = lane >> 4, l16 = lane & 15;
    int bm = blockIdx.y * 128, bn = blockIdx.x * 128;
    int wm = (w & 1) * 64, wn = (w >> 1) * 64;
    int lr = lane >> 2;        // staging row within 16-row group
    int lk = (lane & 3) * 8;   // staging k offset

    floatx4 acc[4][4];
    #pragma unroll
    for (int i = 0; i < 4; ++i)
        #pragma unroll
        for (int j = 0; j < 4; ++j) acc[i][j] = (floatx4){0.f, 0.f, 0.f, 0.f};

    for (int k0 = 0; k0 < K; k0 += 32) {
        // wave w stages A rows [w*32, w*32+32) and B rows likewise; 16 rows/inst
        #pragma unroll
        for (int i = 0; i < 2; ++i) {
            int row = w * 32 + i * 16;
            async16(A + (size_t)(bm + row + lr) * K + k0 + lk, &As[row * 32]);
            async16(Bt + (size_t)(bn + row + lr) * K + k0 + lk, &Bs[row * 32]);
        }
        __syncthreads();

        short8 a[4], b[4];
        #pragma unroll
        for (int mi = 0; mi < 4; ++mi)
            a[mi] = *(short8*)(&As[(wm + mi * 16 + l16) * 32 + quad * 8]);
        #pragma unroll
        for (int ni = 0; ni < 4; ++ni)
            b[ni] = *(short8*)(&Bs[(wn + ni * 16 + l16) * 32 + quad * 8]);
        #pragma unroll
        for (int mi = 0; mi < 4; ++mi)
            #pragma unroll
            for (int ni = 0; ni < 4; ++ni)
                acc[mi][ni] = __builtin_amdgcn_mfma_f32_16x16x32_bf16(a[mi], b[ni], acc[mi][ni], 0, 0, 0);
        __syncthreads();
    }

    // store + fused alpha dots
    #pragma unroll
    for (int mi = 0; mi < 4; ++mi) {
        #pragma unroll
        for (int r = 0; r < 4; ++r) {
            int row = bm + wm + mi * 16 + quad * 4 + r;
            float ps = 0.f, pd = 0.f;
            #pragma unroll
            for (int ni = 0; ni < 4; ++ni) {
                int col = bn + wn + ni * 16 + l16;
                if (col < N) {
                    float v = acc[mi][ni][r];
                    ps += v * a_s[col];
                    pd += v * a_d[col];
                    if (row < M) {
                        if constexpr (OUT_BF16)
                            ((unsigned short*)Cp)[(size_t)row * N + col] = f2bf(v);
                        else
                            ((float*)Cp)[(size_t)row * N + col] = v;
                    }
                }
            }
            #pragma unroll
            for (int msk = 1; msk <= 8; msk <<= 1) {
                ps += __shfl_xor(ps, msk);
                pd += __shfl_xor(pd, msk);
            }
            if (l16 == 0 && row < M) {
                atomicAdd(&als[row], ps);
                atomicAdd(&ald[row], pd);
            }
        }
    }
}

// ---------------- softmax-attention aggregation ----------------
// One wave per node; lane-parallel weights, shuffle-broadcast gather, unroll x4.
template <int DOUT, bool RELU, bool LSM, bool IN_BF16, bool OUT_BF16>
__global__ __launch_bounds__(256) void agg_kernel(const void* __restrict__ h,
                                                  const float* __restrict__ as,
                                                  const float* __restrict__ ad,
                                                  const int* __restrict__ rowptr,
                                                  const int* __restrict__ csr_src,
                                                  const float* __restrict__ bias,
                                                  void* __restrict__ outp) {
    constexpr int C = (DOUT + 63) / 64;
    int wave = threadIdx.x >> 6, lane = threadIdx.x & 63;
    int node = blockIdx.x * 4 + wave;
    if (node >= N_NODES) return;
    int beg = rowptr[node], end = rowptr[node + 1];
    float adi = ad[node];

    int k0 = beg + lane;
    bool has0 = k0 < end;
    int sj = has0 ? csr_src[k0] : 0;
    float ej = -INFINITY;
    if (has0) ej = leaky(as[sj] + adi);

    float m = ej;
    for (int k = k0 + 64; k < end; k += 64) m = fmaxf(m, leaky(as[csr_src[k]] + adi));
    #pragma unroll
    for (int off = 32; off; off >>= 1) m = fmaxf(m, __shfl_xor(m, off));

    float den = has0 ? expf(ej - m) : 0.f;
    for (int k = k0 + 64; k < end; k += 64) den += expf(leaky(as[csr_src[k]] + adi) - m);
    #pragma unroll
    for (int off = 32; off; off >>= 1) den += __shfl_xor(den, off);
    float invden = 1.f / den;

    float wgt = has0 ? expf(ej - m) * invden : 0.f;

    float acc[C];
    #pragma unroll
    for (int c = 0; c < C; ++c) acc[c] = 0.f;

    auto fetch = [&](int s, float* f) {
        if constexpr (IN_BF16) {
            const unsigned short* hr = (const unsigned short*)h + (size_t)s * DOUT + lane * C;
            if constexpr (C == 8) {
                uint4 v = *(const uint4*)hr;
                f[0] = bflo(v.x); f[1] = bfhi(v.x); f[2] = bflo(v.y); f[3] = bfhi(v.y);
                f[4] = bflo(v.z); f[5] = bfhi(v.z); f[6] = bflo(v.w); f[7] = bfhi(v.w);
            } else {
                uint2 v = *(const uint2*)hr;
                f[0] = bflo(v.x); f[1] = bfhi(v.x); f[2] = bflo(v.y); f[3] = bfhi(v.y);
            }
        } else {
            if (lane < DOUT) f[0] = ((const float*)h)[(size_t)s * DOUT + lane];
            else f[0] = 0.f;
        }
    };

    int cnt0 = min(64, end - beg);
    int j = 0;
    for (; j + 3 < cnt0; j += 4) {
        int s0 = __shfl(sj, j), s1 = __shfl(sj, j + 1), s2 = __shfl(sj, j + 2), s3 = __shfl(sj, j + 3);
        float a0 = __shfl(wgt, j), a1 = __shfl(wgt, j + 1), a2 = __shfl(wgt, j + 2), a3 = __shfl(wgt, j + 3);
        float f0[C], f1[C], f2[C], f3[C];
        fetch(s0, f0); fetch(s1, f1); fetch(s2, f2); fetch(s3, f3);
        #pragma unroll
        for (int c = 0; c < C; ++c) acc[c] += a0 * f0[c] + a1 * f1[c] + a2 * f2[c] + a3 * f3[c];
    }
    for (; j < cnt0; ++j) {
        int s0 = __shfl(sj, j);
        float a0 = __shfl(wgt, j);
        float f0[C];
        fetch(s0, f0);
        #pragma unroll
        for (int c = 0; c < C; ++c) acc[c] += a0 * f0[c];
    }
    // rare: degree > 64
    for (int base = beg + 64; base < end; base += 64) {
        int cnt = min(64, end - base);
        int sx = 0; float wx = 0.f;
        if (lane < cnt) {
            sx = csr_src[base + lane];
            wx = expf(leaky(as[sx] + adi) - m) * invden;
        }
        for (int jj = 0; jj < cnt; ++jj) {
            int s0 = __shfl(sx, jj);
            float a0 = __shfl(wx, jj);
            float f0[C];
            fetch(s0, f0);
            #pragma unroll
            for (int c = 0; c < C; ++c) acc[c] += a0 * f0[c];
        }
    }

    if constexpr (!LSM) {
        #pragma unroll
        for (int c = 0; c < C; ++c) {
            int col = lane * C + c;
            if (DOUT % 64 == 0 || col < DOUT) {
                float v = acc[c] + bias[col];
                if (RELU) v = fmaxf(v, 0.f);
                if constexpr (OUT_BF16)
                    ((unsigned short*)outp)[(size_t)node * DOUT + col] = f2bf(v);
                else
                    ((float*)outp)[(size_t)node * DOUT + col] = v;
            }
        }
    } else {
        float v = (lane < DOUT) ? (acc[0] + bias[lane]) : -INFINITY;
        float mm = v;
        #pragma unroll
        for (int off = 32; off; off >>= 1) mm = fmaxf(mm, __shfl_xor(mm, off));
        float ex = (lane < DOUT) ? expf(v - mm) : 0.f;
        float Z = ex;
        #pragma unroll
        for (int off = 32; off; off >>= 1) Z += __shfl_xor(Z, off);
        if (lane < DOUT) ((float*)outp)[(size_t)node * DOUT + lane] = v - mm - logf(Z);
    }
}

// ---------------- launch ----------------

extern "C" void kernel_launch(void* const* d_in, const int* in_sizes, int n_in,
                              void* d_out, int out_size, void* d_ws, size_t ws_size,
                              hipStream_t stream) {
    const float* x   = (const float*)d_in[0];
    const int*   ei  = (const int*)d_in[1];
    const float* W1  = (const float*)d_in[2];
    const float* a1s = (const float*)d_in[3];
    const float* a1d = (const float*)d_in[4];
    const float* b1  = (const float*)d_in[5];
    const float* W2  = (const float*)d_in[6];
    const float* a2s = (const float*)d_in[7];
    const float* a2d = (const float*)d_in[8];
    const float* b2  = (const float*)d_in[9];
    const float* W3  = (const float*)d_in[10];
    const float* a3s = (const float*)d_in[11];
    const float* a3d = (const float*)d_in[12];
    const float* b3  = (const float*)d_in[13];
    float* out = (float*)d_out;

    char* ws = (char*)d_ws;
    size_t off = 0;
    auto alloc = [&](size_t bytes) {
        void* p = ws + off;
        off = (off + bytes + 255) & ~(size_t)255;
        return p;
    };
    int*            deg      = (int*)alloc(N_NODES * 4);
    int*            writeptr = (int*)alloc(N_NODES * 4);
    int*            rowptr   = (int*)alloc((N_NODES + 1) * 4);
    int*            csr_src  = (int*)alloc((size_t)ET * 4);
    float*          alph     = (float*)alloc((size_t)6 * N_NODES * 4);  // als/ald x3 layers
    unsigned short* xb       = (unsigned short*)alloc((size_t)N_NODES * F_IN * 2);
    unsigned short* w1t      = (unsigned short*)alloc((size_t)H1 * F_IN * 2);
    unsigned short* w2t      = (unsigned short*)alloc((size_t)H2 * H1 * 2);
    unsigned short* w3t      = (unsigned short*)alloc((size_t)N_CLS * H2 * 2);
    unsigned short* hb16     = (unsigned short*)alloc((size_t)N_NODES * H1 * 2);
    unsigned short* gbuf     = (unsigned short*)alloc((size_t)N_NODES * H1 * 2);
    float*          h3       = (float*)alloc((size_t)N_NODES * N_CLS * 4);
    (void)alloc(128 * 1024);  // slack for OOB tile reads on the last buffer

    float* als1 = alph + 0 * N_NODES; float* ald1 = alph + 1 * N_NODES;
    float* als2 = alph + 2 * N_NODES; float* ald2 = alph + 3 * N_NODES;
    float* als3 = alph + 4 * N_NODES; float* ald3 = alph + 5 * N_NODES;

    // --- CSR by destination + zero alpha accumulators ---
    zero_kernel<<<(6 * N_NODES + 255) / 256, 256, 0, stream>>>(deg, alph);
    count_deg_kernel<<<(ET + 255) / 256, 256, 0, stream>>>(ei, deg);
    scan_kernel<<<1, 1024, 0, stream>>>(deg, rowptr, writeptr);
    fill_kernel<<<(ET + 255) / 256, 256, 0, stream>>>(ei, writeptr, csr_src);

    // --- casts ---
    cast_bf16_kernel<<<((size_t)N_NODES * F_IN + 255) / 256, 256, 0, stream>>>(x, xb, N_NODES * F_IN);
    castT_kernel<<<(F_IN * H1 + 255) / 256, 256, 0, stream>>>(W1, w1t, F_IN, H1);
    castT_kernel<<<(H1 * H2 + 255) / 256, 256, 0, stream>>>(W2, w2t, H1, H2);
    castT_kernel<<<(H2 * N_CLS + 255) / 256, 256, 0, stream>>>(W3, w3t, H2, N_CLS);

    dim3 blk(256);
    int nodeblocks = (N_NODES + 3) / 4;
    int mtiles = (N_NODES + 127) / 128;  // 157

    // --- layer 1 ---
    gemm_mfma<true><<<dim3(H1 / 128, mtiles), blk, 0, stream>>>(
        xb, w1t, hb16, a1s, a1d, als1, ald1, N_NODES, F_IN, H1);
    agg_kernel<H1, true, false, true, true><<<nodeblocks, blk, 0, stream>>>(
        hb16, als1, ald1, rowptr, csr_src, b1, gbuf);

    // --- layer 2 ---
    gemm_mfma<true><<<dim3(H2 / 128, mtiles), blk, 0, stream>>>(
        gbuf, w2t, hb16, a2s, a2d, als2, ald2, N_NODES, H1, H2);
    agg_kernel<H2, true, false, true, true><<<nodeblocks, blk, 0, stream>>>(
        hb16, als2, ald2, rowptr, csr_src, b2, gbuf);

    // --- layer 3 (fp32 h, fused log_softmax in agg) ---
    gemm_mfma<false><<<dim3(1, mtiles), blk, 0, stream>>>(
        gbuf, w3t, h3, a3s, a3d, als3, ald3, N_NODES, H2, N_CLS);
    agg_kernel<N_CLS, false, true, false, false><<<nodeblocks, blk, 0, stream>>>(
        h3, als3, ald3, rowptr, csr_src, b3, out);
}

// Round 5
// 318.670 us; speedup vs baseline: 1.1217x; 1.1217x over previous
//
#include <hip/hip_runtime.h>
#include <math.h>

#define N_NODES 20000
#define N_EDGESC 320000
#define ET (N_EDGESC + N_NODES)   // 340000 incl. self-loops
#define F_IN 128
#define H1 512
#define H2 256
#define N_CLS 40
#define NEG_SLOPE 0.2f

typedef __attribute__((ext_vector_type(8))) short short8;
typedef __attribute__((ext_vector_type(4))) float floatx4;

__device__ __forceinline__ unsigned short f2bf(float x) {
    unsigned u = __float_as_uint(x);
    unsigned r = (u + 0x7fffu + ((u >> 16) & 1u)) >> 16;  // RNE
    return (unsigned short)r;
}
__device__ __forceinline__ float bflo(unsigned v) { return __uint_as_float(v << 16); }
__device__ __forceinline__ float bfhi(unsigned v) { return __uint_as_float(v & 0xffff0000u); }
__device__ __forceinline__ float leaky(float e) { return (e > 0.f) ? e : e * NEG_SLOPE; }

// ---------------- CSR build ----------------

__global__ void zero_kernel(int* __restrict__ deg, float* __restrict__ alph) {
    int i = blockIdx.x * blockDim.x + threadIdx.x;
    if (i < N_NODES) deg[i] = 0;
    if (i < 6 * N_NODES) alph[i] = 0.f;
}

__global__ void count_deg_kernel(const int* __restrict__ ei, int* __restrict__ deg) {
    int e = blockIdx.x * blockDim.x + threadIdx.x;
    if (e >= ET) return;
    int d = (e < N_EDGESC) ? ei[N_EDGESC + e] : (e - N_EDGESC);
    atomicAdd(&deg[d], 1);
}

__global__ __launch_bounds__(1024) void scan_kernel(const int* __restrict__ deg,
                                                    int* __restrict__ rowptr,
                                                    int* __restrict__ writeptr) {
    __shared__ int sums[1024];
    int t = threadIdx.x;
    const int per = (N_NODES + 1023) / 1024;  // 20
    int base = t * per;
    int local = 0;
    for (int i = 0; i < per; ++i) {
        int idx = base + i;
        if (idx < N_NODES) local += deg[idx];
    }
    sums[t] = local;
    __syncthreads();
    for (int off = 1; off < 1024; off <<= 1) {
        int add = (t >= off) ? sums[t - off] : 0;
        __syncthreads();
        sums[t] += add;
        __syncthreads();
    }
    int run = sums[t] - local;
    for (int i = 0; i < per; ++i) {
        int idx = base + i;
        if (idx < N_NODES) {
            rowptr[idx] = run;
            writeptr[idx] = run;
            run += deg[idx];
        }
    }
    if (t == 1023) rowptr[N_NODES] = sums[1023];
}

__global__ void fill_kernel(const int* __restrict__ ei, int* __restrict__ writeptr,
                            int* __restrict__ csr_src) {
    int e = blockIdx.x * blockDim.x + threadIdx.x;
    if (e >= ET) return;
    int s, d;
    if (e < N_EDGESC) { s = ei[e]; d = ei[N_EDGESC + e]; }
    else { s = d = e - N_EDGESC; }
    int pos = atomicAdd(&writeptr[d], 1);
    csr_src[pos] = s;
}

// ---------------- casts ----------------

__global__ void cast_bf16_kernel(const float* __restrict__ in, unsigned short* __restrict__ out, int n) {
    int i = blockIdx.x * blockDim.x + threadIdx.x;
    if (i < n) out[i] = f2bf(in[i]);
}

__global__ void castT_kernel(const float* __restrict__ W, unsigned short* __restrict__ Wt,
                             int K, int N) {
    int i = blockIdx.x * blockDim.x + threadIdx.x;
    if (i >= K * N) return;
    int k = i / N, n = i - k * N;
    Wt[n * K + k] = f2bf(W[i]);
}

// ---------------- MFMA GEMM, 128x64 tile, BK=32, VGPR-staged LDS, reg dbuf --
// C(MxN) = A(MxK bf16 rm) * Bt(NxK bf16 rm). Fused per-row alpha dots:
// als[row] += sum_col C[row,col]*a_s[col], via quad shuffle-reduce + atomic.
#define LDT 40  // padded LDS stride (bf16) per 32-wide k tile

template <bool OUT_BF16>
__global__ __launch_bounds__(256) void gemm_mfma(const unsigned short* __restrict__ A,
                                                 const unsigned short* __restrict__ Bt,
                                                 void* __restrict__ Cp,
                                                 const float* __restrict__ a_s,
                                                 const float* __restrict__ a_d,
                                                 float* __restrict__ als,
                                                 float* __restrict__ ald,
                                                 int M, int K, int N) {
    __shared__ unsigned short As[128 * LDT];
    __shared__ unsigned short Bs[64 * LDT];
    int t = threadIdx.x;
    int w = t >> 6, lane = t & 63;
    int quad = lane >> 4, l16 = lane & 15;
    int bm = blockIdx.y * 128, bn = blockIdx.x * 64;

    // staging indices (uint4 = 8 bf16): A has 512 loads (2/thread), B has 256 (1/thread)
    int ar0 = t >> 2;                 // A load 0: row t/4
    int ar1 = (t + 256) >> 2;         // A load 1
    int ak = (t & 3) * 8;             // k offset within BK for both
    int br = t >> 2;                  // B row (0..63)

    floatx4 acc[2][4];
    #pragma unroll
    for (int i = 0; i < 2; ++i)
        #pragma unroll
        for (int j = 0; j < 4; ++j) acc[i][j] = (floatx4){0.f, 0.f, 0.f, 0.f};

    // prefetch k0 = 0 into registers
    uint4 pa0 = {0,0,0,0}, pa1 = {0,0,0,0}, pb = {0,0,0,0};
    {
        int gm0 = bm + ar0, gm1 = bm + ar1, gn = bn + br;
        if (gm0 < M) pa0 = *(const uint4*)(A + (size_t)gm0 * K + ak);
        if (gm1 < M) pa1 = *(const uint4*)(A + (size_t)gm1 * K + ak);
        if (gn < N)  pb  = *(const uint4*)(Bt + (size_t)gn * K + ak);
    }

    for (int k0 = 0; k0 < K; k0 += 32) {
        *(uint4*)(&As[ar0 * LDT + ak]) = pa0;
        *(uint4*)(&As[ar1 * LDT + ak]) = pa1;
        *(uint4*)(&Bs[br * LDT + ak])  = pb;
        __syncthreads();

        // issue next tile's global loads early (overlap with ds_read + MFMA)
        int kn = k0 + 32;
        if (kn < K) {
            int gm0 = bm + ar0, gm1 = bm + ar1, gn = bn + br;
            pa0 = (gm0 < M) ? *(const uint4*)(A + (size_t)gm0 * K + kn + ak) : (uint4){0,0,0,0};
            pa1 = (gm1 < M) ? *(const uint4*)(A + (size_t)gm1 * K + kn + ak) : (uint4){0,0,0,0};
            pb  = (gn < N)  ? *(const uint4*)(Bt + (size_t)gn * K + kn + ak) : (uint4){0,0,0,0};
        }

        short8 a[2], b[4];
        #pragma unroll
        for (int mi = 0; mi < 2; ++mi)
            a[mi] = *(short8*)(&As[(w * 32 + mi * 16 + l16) * LDT + quad * 8]);
        #pragma unroll
        for (int ni = 0; ni < 4; ++ni)
            b[ni] = *(short8*)(&Bs[(ni * 16 + l16) * LDT + quad * 8]);
        #pragma unroll
        for (int mi = 0; mi < 2; ++mi)
            #pragma unroll
            for (int ni = 0; ni < 4; ++ni)
                acc[mi][ni] = __builtin_amdgcn_mfma_f32_16x16x32_bf16(a[mi], b[ni], acc[mi][ni], 0, 0, 0);
        __syncthreads();
    }

    // store + fused alpha dots (wave w owns rows [w*32, w*32+32))
    #pragma unroll
    for (int mi = 0; mi < 2; ++mi) {
        #pragma unroll
        for (int r = 0; r < 4; ++r) {
            int row = bm + w * 32 + mi * 16 + quad * 4 + r;
            float ps = 0.f, pd = 0.f;
            #pragma unroll
            for (int ni = 0; ni < 4; ++ni) {
                int col = bn + ni * 16 + l16;
                if (col < N) {
                    float v = acc[mi][ni][r];
                    ps += v * a_s[col];
                    pd += v * a_d[col];
                    if (row < M) {
                        if constexpr (OUT_BF16)
                            ((unsigned short*)Cp)[(size_t)row * N + col] = f2bf(v);
                        else
                            ((float*)Cp)[(size_t)row * N + col] = v;
                    }
                }
            }
            #pragma unroll
            for (int msk = 1; msk <= 8; msk <<= 1) {
                ps += __shfl_xor(ps, msk);
                pd += __shfl_xor(pd, msk);
            }
            if (l16 == 0 && row < M) {
                atomicAdd(&als[row], ps);
                atomicAdd(&ald[row], pd);
            }
        }
    }
}

// ---------------- softmax-attention aggregation ----------------
// One wave per node; lane-parallel weights, shuffle-broadcast gather, unroll x4.
template <int DOUT, bool RELU, bool LSM, bool IN_BF16, bool OUT_BF16>
__global__ __launch_bounds__(256) void agg_kernel(const void* __restrict__ h,
                                                  const float* __restrict__ as,
                                                  const float* __restrict__ ad,
                                                  const int* __restrict__ rowptr,
                                                  const int* __restrict__ csr_src,
                                                  const float* __restrict__ bias,
                                                  void* __restrict__ outp) {
    constexpr int C = (DOUT + 63) / 64;
    int wave = threadIdx.x >> 6, lane = threadIdx.x & 63;
    int node = blockIdx.x * 4 + wave;
    if (node >= N_NODES) return;
    int beg = rowptr[node], end = rowptr[node + 1];
    float adi = ad[node];

    int k0 = beg + lane;
    bool has0 = k0 < end;
    int sj = has0 ? csr_src[k0] : 0;
    float ej = -INFINITY;
    if (has0) ej = leaky(as[sj] + adi);

    float m = ej;
    for (int k = k0 + 64; k < end; k += 64) m = fmaxf(m, leaky(as[csr_src[k]] + adi));
    #pragma unroll
    for (int off = 32; off; off >>= 1) m = fmaxf(m, __shfl_xor(m, off));

    float den = has0 ? expf(ej - m) : 0.f;
    for (int k = k0 + 64; k < end; k += 64) den += expf(leaky(as[csr_src[k]] + adi) - m);
    #pragma unroll
    for (int off = 32; off; off >>= 1) den += __shfl_xor(den, off);
    float invden = 1.f / den;

    float wgt = has0 ? expf(ej - m) * invden : 0.f;

    float acc[C];
    #pragma unroll
    for (int c = 0; c < C; ++c) acc[c] = 0.f;

    auto fetch = [&](int s, float* f) {
        if constexpr (IN_BF16) {
            const unsigned short* hr = (const unsigned short*)h + (size_t)s * DOUT + lane * C;
            if constexpr (C == 8) {
                uint4 v = *(const uint4*)hr;
                f[0] = bflo(v.x); f[1] = bfhi(v.x); f[2] = bflo(v.y); f[3] = bfhi(v.y);
                f[4] = bflo(v.z); f[5] = bfhi(v.z); f[6] = bflo(v.w); f[7] = bfhi(v.w);
            } else {
                uint2 v = *(const uint2*)hr;
                f[0] = bflo(v.x); f[1] = bfhi(v.x); f[2] = bflo(v.y); f[3] = bfhi(v.y);
            }
        } else {
            if (lane < DOUT) f[0] = ((const float*)h)[(size_t)s * DOUT + lane];
            else f[0] = 0.f;
        }
    };

    int cnt0 = min(64, end - beg);
    int j = 0;
    for (; j + 3 < cnt0; j += 4) {
        int s0 = __shfl(sj, j), s1 = __shfl(sj, j + 1), s2 = __shfl(sj, j + 2), s3 = __shfl(sj, j + 3);
        float a0 = __shfl(wgt, j), a1 = __shfl(wgt, j + 1), a2 = __shfl(wgt, j + 2), a3 = __shfl(wgt, j + 3);
        float f0[C], f1[C], f2[C], f3[C];
        fetch(s0, f0); fetch(s1, f1); fetch(s2, f2); fetch(s3, f3);
        #pragma unroll
        for (int c = 0; c < C; ++c) acc[c] += a0 * f0[c] + a1 * f1[c] + a2 * f2[c] + a3 * f3[c];
    }
    for (; j < cnt0; ++j) {
        int s0 = __shfl(sj, j);
        float a0 = __shfl(wgt, j);
        float f0[C];
        fetch(s0, f0);
        #pragma unroll
        for (int c = 0; c < C; ++c) acc[c] += a0 * f0[c];
    }
    // rare: degree > 64
    for (int base = beg + 64; base < end; base += 64) {
        int cnt = min(64, end - base);
        int sx = 0; float wx = 0.f;
        if (lane < cnt) {
            sx = csr_src[base + lane];
            wx = expf(leaky(as[sx] + adi) - m) * invden;
        }
        for (int jj = 0; jj < cnt; ++jj) {
            int s0 = __shfl(sx, jj);
            float a0 = __shfl(wx, jj);
            float f0[C];
            fetch(s0, f0);
            #pragma unroll
            for (int c = 0; c < C; ++c) acc[c] += a0 * f0[c];
        }
    }

    if constexpr (!LSM) {
        #pragma unroll
        for (int c = 0; c < C; ++c) {
            int col = lane * C + c;
            if (DOUT % 64 == 0 || col < DOUT) {
                float v = acc[c] + bias[col];
                if (RELU) v = fmaxf(v, 0.f);
                if constexpr (OUT_BF16)
                    ((unsigned short*)outp)[(size_t)node * DOUT + col] = f2bf(v);
                else
                    ((float*)outp)[(size_t)node * DOUT + col] = v;
            }
        }
    } else {
        float v = (lane < DOUT) ? (acc[0] + bias[lane]) : -INFINITY;
        float mm = v;
        #pragma unroll
        for (int off = 32; off; off >>= 1) mm = fmaxf(mm, __shfl_xor(mm, off));
        float ex = (lane < DOUT) ? expf(v - mm) : 0.f;
        float Z = ex;
        #pragma unroll
        for (int off = 32; off; off >>= 1) Z += __shfl_xor(Z, off);
        if (lane < DOUT) ((float*)outp)[(size_t)node * DOUT + lane] = v - mm - logf(Z);
    }
}

// ---------------- launch ----------------

extern "C" void kernel_launch(void* const* d_in, const int* in_sizes, int n_in,
                              void* d_out, int out_size, void* d_ws, size_t ws_size,
                              hipStream_t stream) {
    const float* x   = (const float*)d_in[0];
    const int*   ei  = (const int*)d_in[1];
    const float* W1  = (const float*)d_in[2];
    const float* a1s = (const float*)d_in[3];
    const float* a1d = (const float*)d_in[4];
    const float* b1  = (const float*)d_in[5];
    const float* W2  = (const float*)d_in[6];
    const float* a2s = (const float*)d_in[7];
    const float* a2d = (const float*)d_in[8];
    const float* b2  = (const float*)d_in[9];
    const float* W3  = (const float*)d_in[10];
    const float* a3s = (const float*)d_in[11];
    const float* a3d = (const float*)d_in[12];
    const float* b3  = (const float*)d_in[13];
    float* out = (float*)d_out;

    char* ws = (char*)d_ws;
    size_t off = 0;
    auto alloc = [&](size_t bytes) {
        void* p = ws + off;
        off = (off + bytes + 255) & ~(size_t)255;
        return p;
    };
    int*            deg      = (int*)alloc(N_NODES * 4);
    int*            writeptr = (int*)alloc(N_NODES * 4);
    int*            rowptr   = (int*)alloc((N_NODES + 1) * 4);
    int*            csr_src  = (int*)alloc((size_t)ET * 4);
    float*          alph     = (float*)alloc((size_t)6 * N_NODES * 4);  // als/ald x3 layers
    unsigned short* xb       = (unsigned short*)alloc((size_t)N_NODES * F_IN * 2);
    unsigned short* w1t      = (unsigned short*)alloc((size_t)H1 * F_IN * 2);
    unsigned short* w2t      = (unsigned short*)alloc((size_t)H2 * H1 * 2);
    unsigned short* w3t      = (unsigned short*)alloc((size_t)N_CLS * H2 * 2);
    unsigned short* hb16     = (unsigned short*)alloc((size_t)N_NODES * H1 * 2);
    unsigned short* gbuf     = (unsigned short*)alloc((size_t)N_NODES * H1 * 2);
    float*          h3       = (float*)alloc((size_t)N_NODES * N_CLS * 4);
    (void)alloc(128 * 1024);  // slack

    float* als1 = alph + 0 * N_NODES; float* ald1 = alph + 1 * N_NODES;
    float* als2 = alph + 2 * N_NODES; float* ald2 = alph + 3 * N_NODES;
    float* als3 = alph + 4 * N_NODES; float* ald3 = alph + 5 * N_NODES;

    // --- CSR by destination + zero alpha accumulators ---
    zero_kernel<<<(6 * N_NODES + 255) / 256, 256, 0, stream>>>(deg, alph);
    count_deg_kernel<<<(ET + 255) / 256, 256, 0, stream>>>(ei, deg);
    scan_kernel<<<1, 1024, 0, stream>>>(deg, rowptr, writeptr);
    fill_kernel<<<(ET + 255) / 256, 256, 0, stream>>>(ei, writeptr, csr_src);

    // --- casts ---
    cast_bf16_kernel<<<((size_t)N_NODES * F_IN + 255) / 256, 256, 0, stream>>>(x, xb, N_NODES * F_IN);
    castT_kernel<<<(F_IN * H1 + 255) / 256, 256, 0, stream>>>(W1, w1t, F_IN, H1);
    castT_kernel<<<(H1 * H2 + 255) / 256, 256, 0, stream>>>(W2, w2t, H1, H2);
    castT_kernel<<<(H2 * N_CLS + 255) / 256, 256, 0, stream>>>(W3, w3t, H2, N_CLS);

    dim3 blk(256);
    int nodeblocks = (N_NODES + 3) / 4;
    int mtiles = (N_NODES + 127) / 128;  // 157

    // --- layer 1 ---
    gemm_mfma<true><<<dim3(H1 / 64, mtiles), blk, 0, stream>>>(
        xb, w1t, hb16, a1s, a1d, als1, ald1, N_NODES, F_IN, H1);
    agg_kernel<H1, true, false, true, true><<<nodeblocks, blk, 0, stream>>>(
        hb16, als1, ald1, rowptr, csr_src, b1, gbuf);

    // --- layer 2 ---
    gemm_mfma<true><<<dim3(H2 / 64, mtiles), blk, 0, stream>>>(
        gbuf, w2t, hb16, a2s, a2d, als2, ald2, N_NODES, H1, H2);
    agg_kernel<H2, true, false, true, true><<<nodeblocks, blk, 0, stream>>>(
        hb16, als2, ald2, rowptr, csr_src, b2, gbuf);

    // --- layer 3 (fp32 h, fused log_softmax in agg) ---
    gemm_mfma<false><<<dim3(1, mtiles), blk, 0, stream>>>(
        gbuf, w3t, h3, a3s, a3d, als3, ald3, N_NODES, H2, N_CLS);
    agg_kernel<N_CLS, false, true, false, false><<<nodeblocks, blk, 0, stream>>>(
        h3, als3, ald3, rowptr, csr_src, b3, out);
}

// Round 6
// 277.900 us; speedup vs baseline: 1.2863x; 1.1467x over previous
//
#include <hip/hip_runtime.h>
#include <math.h>

#define N_NODES 20000
#define N_EDGESC 320000
#define ET (N_EDGESC + N_NODES)   // 340000 incl. self-loops
#define F_IN 128
#define H1 512
#define H2 256
#define N_CLS 40
#define NEG_SLOPE 0.2f

typedef __attribute__((ext_vector_type(8))) short short8;
typedef __attribute__((ext_vector_type(4))) float floatx4;

__device__ __forceinline__ unsigned short f2bf(float x) {
    unsigned u = __float_as_uint(x);
    unsigned r = (u + 0x7fffu + ((u >> 16) & 1u)) >> 16;  // RNE
    return (unsigned short)r;
}
__device__ __forceinline__ float bflo(unsigned v) { return __uint_as_float(v << 16); }
__device__ __forceinline__ float bfhi(unsigned v) { return __uint_as_float(v & 0xffff0000u); }
__device__ __forceinline__ float leaky(float e) { return (e > 0.f) ? e : e * NEG_SLOPE; }

// ---------------- CSR build ----------------

__global__ void zero_kernel(int* __restrict__ deg) {
    int i = blockIdx.x * blockDim.x + threadIdx.x;
    if (i < N_NODES) deg[i] = 0;
}

__global__ void count_deg_kernel(const int* __restrict__ ei, int* __restrict__ deg) {
    int e = blockIdx.x * blockDim.x + threadIdx.x;
    if (e >= ET) return;
    int d = (e < N_EDGESC) ? ei[N_EDGESC + e] : (e - N_EDGESC);
    atomicAdd(&deg[d], 1);
}

__global__ __launch_bounds__(1024) void scan_kernel(const int* __restrict__ deg,
                                                    int* __restrict__ rowptr,
                                                    int* __restrict__ writeptr) {
    __shared__ int sums[1024];
    int t = threadIdx.x;
    const int per = (N_NODES + 1023) / 1024;  // 20
    int base = t * per;
    int local = 0;
    for (int i = 0; i < per; ++i) {
        int idx = base + i;
        if (idx < N_NODES) local += deg[idx];
    }
    sums[t] = local;
    __syncthreads();
    for (int off = 1; off < 1024; off <<= 1) {
        int add = (t >= off) ? sums[t - off] : 0;
        __syncthreads();
        sums[t] += add;
        __syncthreads();
    }
    int run = sums[t] - local;
    for (int i = 0; i < per; ++i) {
        int idx = base + i;
        if (idx < N_NODES) {
            rowptr[idx] = run;
            writeptr[idx] = run;
            run += deg[idx];
        }
    }
    if (t == 1023) rowptr[N_NODES] = sums[1023];
}

__global__ void fill_kernel(const int* __restrict__ ei, int* __restrict__ writeptr,
                            int* __restrict__ csr_src) {
    int e = blockIdx.x * blockDim.x + threadIdx.x;
    if (e >= ET) return;
    int s, d;
    if (e < N_EDGESC) { s = ei[e]; d = ei[N_EDGESC + e]; }
    else { s = d = e - N_EDGESC; }
    int pos = atomicAdd(&writeptr[d], 1);
    csr_src[pos] = s;
}

// ---------------- casts ----------------

__global__ void cast_bf16_kernel(const float* __restrict__ in, unsigned short* __restrict__ out, int n) {
    int i = blockIdx.x * blockDim.x + threadIdx.x;
    if (i < n) out[i] = f2bf(in[i]);
}

// all three W -> W^T bf16 in one launch
__global__ void castT_all_kernel(const float* __restrict__ W1, unsigned short* __restrict__ w1t,
                                 const float* __restrict__ W2, unsigned short* __restrict__ w2t,
                                 const float* __restrict__ W3, unsigned short* __restrict__ w3t) {
    int i = blockIdx.x * blockDim.x + threadIdx.x;
    if (i < F_IN * H1) {
        int k = i >> 9, n = i & 511;
        w1t[n * F_IN + k] = f2bf(W1[i]);
    } else if (i < F_IN * H1 + H1 * H2) {
        int j = i - F_IN * H1;
        int k = j >> 8, n = j & 255;
        w2t[n * H1 + k] = f2bf(W2[j]);
    } else if (i < F_IN * H1 + H1 * H2 + H2 * N_CLS) {
        int j = i - (F_IN * H1 + H1 * H2);
        int k = j / N_CLS, n = j - k * N_CLS;
        w3t[n * H2 + k] = f2bf(W3[j]);
    }
}

// ---------------- wa = W @ a_{s,d} (fp32), 6 vectors packed in wab ----------
// wab layout: [0:128) w1s | [128:256) w1d | [256:768) w2s | [768:1280) w2d
//             | [1280:1536) w3s | [1536:1792) w3d
__global__ __launch_bounds__(256) void wa_kernel(const float* __restrict__ W1, const float* __restrict__ a1s, const float* __restrict__ a1d,
                                                 const float* __restrict__ W2, const float* __restrict__ a2s, const float* __restrict__ a2d,
                                                 const float* __restrict__ W3, const float* __restrict__ a3s, const float* __restrict__ a3d,
                                                 float* __restrict__ wab) {
    int wave = threadIdx.x >> 6, lane = threadIdx.x & 63;
    int row = blockIdx.x * 4 + wave;  // 0..895
    const float *W, *vs, *vd;
    float *os, *od;
    int N, k;
    if (row < 128)      { k = row;       W = W1; vs = a1s; vd = a1d; os = wab;        od = wab + 128;  N = H1; }
    else if (row < 640) { k = row - 128; W = W2; vs = a2s; vd = a2d; os = wab + 256;  od = wab + 768;  N = H2; }
    else if (row < 896) { k = row - 640; W = W3; vs = a3s; vd = a3d; os = wab + 1280; od = wab + 1536; N = N_CLS; }
    else return;
    const float* r = W + (size_t)k * N;
    float ss = 0.f, sd = 0.f;
    for (int n = lane; n < N; n += 64) {
        float v = r[n];
        ss += v * vs[n];
        sd += v * vd[n];
    }
    #pragma unroll
    for (int off = 32; off; off >>= 1) {
        ss += __shfl_xor(ss, off);
        sd += __shfl_xor(sd, off);
    }
    if (lane == 0) { os[k] = ss; od[k] = sd; }
}

// ---------------- alpha GEMV: als[i] = in[i,:].wvs, ald[i] = in[i,:].wvd ----
template <int DIN, bool IN_BF16>
__global__ __launch_bounds__(256) void gemv2_kernel(const void* __restrict__ in,
                                                    const float* __restrict__ wvs,
                                                    const float* __restrict__ wvd,
                                                    float* __restrict__ als,
                                                    float* __restrict__ ald) {
    int wave = threadIdx.x >> 6, lane = threadIdx.x & 63;
    int node = blockIdx.x * 4 + wave;
    if (node >= N_NODES) return;
    float ss = 0.f, sd = 0.f;
    constexpr int C = DIN / 64;
    if constexpr (IN_BF16) {
        const unsigned short* r = (const unsigned short*)in + (size_t)node * DIN + lane * C;
        float f[C];
        if constexpr (C == 8) {
            uint4 v = *(const uint4*)r;
            f[0] = bflo(v.x); f[1] = bfhi(v.x); f[2] = bflo(v.y); f[3] = bfhi(v.y);
            f[4] = bflo(v.z); f[5] = bfhi(v.z); f[6] = bflo(v.w); f[7] = bfhi(v.w);
        } else {
            uint2 v = *(const uint2*)r;
            f[0] = bflo(v.x); f[1] = bfhi(v.x); f[2] = bflo(v.y); f[3] = bfhi(v.y);
        }
        #pragma unroll
        for (int c = 0; c < C; ++c) {
            ss += f[c] * wvs[lane * C + c];
            sd += f[c] * wvd[lane * C + c];
        }
    } else {
        const float* r = (const float*)in + (size_t)node * DIN + lane * C;  // C==2
        float2 v = *(const float2*)r;
        ss = v.x * wvs[lane * 2] + v.y * wvs[lane * 2 + 1];
        sd = v.x * wvd[lane * 2] + v.y * wvd[lane * 2 + 1];
    }
    #pragma unroll
    for (int off = 32; off; off >>= 1) {
        ss += __shfl_xor(ss, off);
        sd += __shfl_xor(sd, off);
    }
    if (lane == 0) { als[node] = ss; ald[node] = sd; }
}

// ---------------- MFMA GEMM, 128x64 tile, BK=32, VGPR-staged LDS, reg dbuf --
// C(MxN) = A(MxK bf16 rm) * Bt(NxK bf16 rm).
// OUT_BF16: LDS-repacked uint4 stores; BIASRELU: v = max(v+bias[col],0).
#define LDT 40   // padded LDS stride (bf16) per 32-wide k tile
#define LSO 66   // epilogue repack stride (bf16)

template <bool BIASRELU, bool OUT_BF16>
__global__ __launch_bounds__(256) void gemm_mfma(const unsigned short* __restrict__ A,
                                                 const unsigned short* __restrict__ Bt,
                                                 void* __restrict__ Cp,
                                                 const float* __restrict__ bias,
                                                 int M, int K, int N) {
    __shared__ unsigned short As[128 * LDT];
    __shared__ unsigned short Bs[64 * LDT];
    __shared__ unsigned short Ls[64 * LSO];
    int t = threadIdx.x;
    int w = t >> 6, lane = t & 63;
    int quad = lane >> 4, l16 = lane & 15;
    int bm = blockIdx.y * 128, bn = blockIdx.x * 64;

    int ar0 = t >> 2;
    int ar1 = (t + 256) >> 2;
    int ak = (t & 3) * 8;
    int br = t >> 2;

    floatx4 acc[2][4];
    #pragma unroll
    for (int i = 0; i < 2; ++i)
        #pragma unroll
        for (int j = 0; j < 4; ++j) acc[i][j] = (floatx4){0.f, 0.f, 0.f, 0.f};

    uint4 pa0 = {0,0,0,0}, pa1 = {0,0,0,0}, pb = {0,0,0,0};
    {
        int gm0 = bm + ar0, gm1 = bm + ar1, gn = bn + br;
        if (gm0 < M) pa0 = *(const uint4*)(A + (size_t)gm0 * K + ak);
        if (gm1 < M) pa1 = *(const uint4*)(A + (size_t)gm1 * K + ak);
        if (gn < N)  pb  = *(const uint4*)(Bt + (size_t)gn * K + ak);
    }

    for (int k0 = 0; k0 < K; k0 += 32) {
        *(uint4*)(&As[ar0 * LDT + ak]) = pa0;
        *(uint4*)(&As[ar1 * LDT + ak]) = pa1;
        *(uint4*)(&Bs[br * LDT + ak])  = pb;
        __syncthreads();

        int kn = k0 + 32;
        if (kn < K) {
            int gm0 = bm + ar0, gm1 = bm + ar1, gn = bn + br;
            pa0 = (gm0 < M) ? *(const uint4*)(A + (size_t)gm0 * K + kn + ak) : (uint4){0,0,0,0};
            pa1 = (gm1 < M) ? *(const uint4*)(A + (size_t)gm1 * K + kn + ak) : (uint4){0,0,0,0};
            pb  = (gn < N)  ? *(const uint4*)(Bt + (size_t)gn * K + kn + ak) : (uint4){0,0,0,0};
        }

        short8 a[2], b[4];
        #pragma unroll
        for (int mi = 0; mi < 2; ++mi)
            a[mi] = *(short8*)(&As[(w * 32 + mi * 16 + l16) * LDT + quad * 8]);
        #pragma unroll
        for (int ni = 0; ni < 4; ++ni)
            b[ni] = *(short8*)(&Bs[(ni * 16 + l16) * LDT + quad * 8]);
        #pragma unroll
        for (int mi = 0; mi < 2; ++mi)
            #pragma unroll
            for (int ni = 0; ni < 4; ++ni)
                acc[mi][ni] = __builtin_amdgcn_mfma_f32_16x16x32_bf16(a[mi], b[ni], acc[mi][ni], 0, 0, 0);
        __syncthreads();
    }

    if constexpr (OUT_BF16) {
        // repack each 64-row half-tile through LDS, store as uint4 (8 bf16)
        #pragma unroll
        for (int mi = 0; mi < 2; ++mi) {
            #pragma unroll
            for (int ni = 0; ni < 4; ++ni) {
                int col = bn + ni * 16 + l16;
                #pragma unroll
                for (int r = 0; r < 4; ++r) {
                    float v = acc[mi][ni][r];
                    if constexpr (BIASRELU) v = fmaxf(v + bias[col], 0.f);
                    Ls[(w * 16 + quad * 4 + r) * LSO + ni * 16 + l16] = f2bf(v);
                }
            }
            __syncthreads();
            #pragma unroll
            for (int i = 0; i < 2; ++i) {
                int idx = t + i * 256;
                int lrow = idx >> 3, c8 = (idx & 7) * 8;
                int grow = bm + (lrow >> 4) * 32 + mi * 16 + (lrow & 15);
                if (grow < M)
                    *(uint4*)((unsigned short*)Cp + (size_t)grow * N + bn + c8) =
                        *(uint4*)(&Ls[lrow * LSO + c8]);
            }
            __syncthreads();
        }
    } else {
        #pragma unroll
        for (int mi = 0; mi < 2; ++mi) {
            #pragma unroll
            for (int r = 0; r < 4; ++r) {
                int row = bm + w * 32 + mi * 16 + quad * 4 + r;
                if (row >= M) continue;
                #pragma unroll
                for (int ni = 0; ni < 4; ++ni) {
                    int col = bn + ni * 16 + l16;
                    if (col < N) ((float*)Cp)[(size_t)row * N + col] = acc[mi][ni][r];
                }
            }
        }
    }
}

// ---------------- softmax-attention aggregation ----------------
// One wave per node; lane-parallel weights, shuffle-broadcast gather, unroll x8.
template <int DOUT, bool BIAS, bool RELU, bool LSM, bool IN_BF16, bool OUT_BF16>
__global__ __launch_bounds__(256) void agg_kernel(const void* __restrict__ h,
                                                  const float* __restrict__ as,
                                                  const float* __restrict__ ad,
                                                  const int* __restrict__ rowptr,
                                                  const int* __restrict__ csr_src,
                                                  const float* __restrict__ bias,
                                                  void* __restrict__ outp) {
    constexpr int C = (DOUT + 63) / 64;
    int wave = threadIdx.x >> 6, lane = threadIdx.x & 63;
    int node = blockIdx.x * 4 + wave;
    if (node >= N_NODES) return;
    int beg = rowptr[node], end = rowptr[node + 1];
    float adi = ad[node];

    int k0 = beg + lane;
    bool has0 = k0 < end;
    int sj = has0 ? csr_src[k0] : 0;
    float ej = -INFINITY;
    if (has0) ej = leaky(as[sj] + adi);

    float m = ej;
    for (int k = k0 + 64; k < end; k += 64) m = fmaxf(m, leaky(as[csr_src[k]] + adi));
    #pragma unroll
    for (int off = 32; off; off >>= 1) m = fmaxf(m, __shfl_xor(m, off));

    float den = has0 ? expf(ej - m) : 0.f;
    for (int k = k0 + 64; k < end; k += 64) den += expf(leaky(as[csr_src[k]] + adi) - m);
    #pragma unroll
    for (int off = 32; off; off >>= 1) den += __shfl_xor(den, off);
    float invden = 1.f / den;

    float wgt = has0 ? expf(ej - m) * invden : 0.f;

    float acc[C];
    #pragma unroll
    for (int c = 0; c < C; ++c) acc[c] = 0.f;

    auto fetch = [&](int s, float* f) {
        if constexpr (IN_BF16) {
            const unsigned short* hr = (const unsigned short*)h + (size_t)s * DOUT + lane * C;
            if constexpr (C == 8) {
                uint4 v = *(const uint4*)hr;
                f[0] = bflo(v.x); f[1] = bfhi(v.x); f[2] = bflo(v.y); f[3] = bfhi(v.y);
                f[4] = bflo(v.z); f[5] = bfhi(v.z); f[6] = bflo(v.w); f[7] = bfhi(v.w);
            } else if constexpr (C == 4) {
                uint2 v = *(const uint2*)hr;
                f[0] = bflo(v.x); f[1] = bfhi(v.x); f[2] = bflo(v.y); f[3] = bfhi(v.y);
            } else {
                unsigned v = *(const unsigned*)hr;
                f[0] = bflo(v); f[1] = bfhi(v);
            }
        } else {
            if (lane < DOUT) f[0] = ((const float*)h)[(size_t)s * DOUT + lane];
            else f[0] = 0.f;
        }
    };

    int cnt0 = min(64, end - beg);
    int j = 0;
    for (; j + 7 < cnt0; j += 8) {
        int s[8]; float a[8]; float f[8][C];
        #pragma unroll
        for (int u = 0; u < 8; ++u) { s[u] = __shfl(sj, j + u); a[u] = __shfl(wgt, j + u); }
        #pragma unroll
        for (int u = 0; u < 8; ++u) fetch(s[u], f[u]);
        #pragma unroll
        for (int u = 0; u < 8; ++u)
            #pragma unroll
            for (int c = 0; c < C; ++c) acc[c] += a[u] * f[u][c];
    }
    for (; j < cnt0; ++j) {
        int s0 = __shfl(sj, j);
        float a0 = __shfl(wgt, j);
        float f0[C];
        fetch(s0, f0);
        #pragma unroll
        for (int c = 0; c < C; ++c) acc[c] += a0 * f0[c];
    }
    // rare: degree > 64
    for (int base = beg + 64; base < end; base += 64) {
        int cnt = min(64, end - base);
        int sx = 0; float wx = 0.f;
        if (lane < cnt) {
            sx = csr_src[base + lane];
            wx = expf(leaky(as[sx] + adi) - m) * invden;
        }
        for (int jj = 0; jj < cnt; ++jj) {
            int s0 = __shfl(sx, jj);
            float a0 = __shfl(wx, jj);
            float f0[C];
            fetch(s0, f0);
            #pragma unroll
            for (int c = 0; c < C; ++c) acc[c] += a0 * f0[c];
        }
    }

    if constexpr (!LSM) {
        #pragma unroll
        for (int c = 0; c < C; ++c) {
            int col = lane * C + c;
            if (DOUT % 64 == 0 || col < DOUT) {
                float v = acc[c];
                if constexpr (BIAS) v += bias[col];
                if constexpr (RELU) v = fmaxf(v, 0.f);
                if constexpr (OUT_BF16)
                    ((unsigned short*)outp)[(size_t)node * DOUT + col] = f2bf(v);
                else
                    ((float*)outp)[(size_t)node * DOUT + col] = v;
            }
        }
    } else {
        float v = (lane < DOUT) ? (acc[0] + bias[lane]) : -INFINITY;
        float mm = v;
        #pragma unroll
        for (int off = 32; off; off >>= 1) mm = fmaxf(mm, __shfl_xor(mm, off));
        float ex = (lane < DOUT) ? expf(v - mm) : 0.f;
        float Z = ex;
        #pragma unroll
        for (int off = 32; off; off >>= 1) Z += __shfl_xor(Z, off);
        if (lane < DOUT) ((float*)outp)[(size_t)node * DOUT + lane] = v - mm - logf(Z);
    }
}

// ---------------- launch ----------------

extern "C" void kernel_launch(void* const* d_in, const int* in_sizes, int n_in,
                              void* d_out, int out_size, void* d_ws, size_t ws_size,
                              hipStream_t stream) {
    const float* x   = (const float*)d_in[0];
    const int*   ei  = (const int*)d_in[1];
    const float* W1  = (const float*)d_in[2];
    const float* a1s = (const float*)d_in[3];
    const float* a1d = (const float*)d_in[4];
    const float* b1  = (const float*)d_in[5];
    const float* W2  = (const float*)d_in[6];
    const float* a2s = (const float*)d_in[7];
    const float* a2d = (const float*)d_in[8];
    const float* b2  = (const float*)d_in[9];
    const float* W3  = (const float*)d_in[10];
    const float* a3s = (const float*)d_in[11];
    const float* a3d = (const float*)d_in[12];
    const float* b3  = (const float*)d_in[13];
    float* out = (float*)d_out;

    char* ws = (char*)d_ws;
    size_t off = 0;
    auto alloc = [&](size_t bytes) {
        void* p = ws + off;
        off = (off + bytes + 255) & ~(size_t)255;
        return p;
    };
    int*            deg      = (int*)alloc(N_NODES * 4);
    int*            writeptr = (int*)alloc(N_NODES * 4);
    int*            rowptr   = (int*)alloc((N_NODES + 1) * 4);
    int*            csr_src  = (int*)alloc((size_t)ET * 4);
    float*          alph     = (float*)alloc((size_t)6 * N_NODES * 4);
    float*          wab      = (float*)alloc(1792 * 4);
    unsigned short* xb       = (unsigned short*)alloc((size_t)N_NODES * F_IN * 2);
    unsigned short* w1t      = (unsigned short*)alloc((size_t)H1 * F_IN * 2);
    unsigned short* w2t      = (unsigned short*)alloc((size_t)H2 * H1 * 2);
    unsigned short* w3t      = (unsigned short*)alloc((size_t)N_CLS * H2 * 2);
    unsigned short* zb       = (unsigned short*)alloc((size_t)N_NODES * F_IN * 2);  // agg(x)
    unsigned short* y1       = (unsigned short*)alloc((size_t)N_NODES * H1 * 2);    // layer-1 out / layer-3 in (aliased y2)
    unsigned short* h2       = (unsigned short*)alloc((size_t)N_NODES * H2 * 2);
    float*          h3       = (float*)alloc((size_t)N_NODES * N_CLS * 4);
    (void)alloc(128 * 1024);  // slack

    unsigned short* y2 = y1;  // y1 fully consumed before y2 is produced

    float* als1 = alph + 0 * N_NODES; float* ald1 = alph + 1 * N_NODES;
    float* als2 = alph + 2 * N_NODES; float* ald2 = alph + 3 * N_NODES;
    float* als3 = alph + 4 * N_NODES; float* ald3 = alph + 5 * N_NODES;

    // --- CSR by destination ---
    zero_kernel<<<(N_NODES + 255) / 256, 256, 0, stream>>>(deg);
    count_deg_kernel<<<(ET + 255) / 256, 256, 0, stream>>>(ei, deg);
    scan_kernel<<<1, 1024, 0, stream>>>(deg, rowptr, writeptr);
    fill_kernel<<<(ET + 255) / 256, 256, 0, stream>>>(ei, writeptr, csr_src);

    // --- casts + wa precompute ---
    cast_bf16_kernel<<<((size_t)N_NODES * F_IN + 255) / 256, 256, 0, stream>>>(x, xb, N_NODES * F_IN);
    castT_all_kernel<<<(F_IN * H1 + H1 * H2 + H2 * N_CLS + 255) / 256, 256, 0, stream>>>(
        W1, w1t, W2, w2t, W3, w3t);
    wa_kernel<<<224, 256, 0, stream>>>(W1, a1s, a1d, W2, a2s, a2d, W3, a3s, a3d, wab);

    dim3 blk(256);
    int nodeblocks = (N_NODES + 3) / 4;
    int mtiles = (N_NODES + 127) / 128;  // 157

    // --- layer 1 (aggregate in input space: out = (sum alpha x_j) W1) ---
    gemv2_kernel<F_IN, false><<<nodeblocks, blk, 0, stream>>>(x, wab, wab + 128, als1, ald1);
    agg_kernel<F_IN, false, false, false, true, true><<<nodeblocks, blk, 0, stream>>>(
        xb, als1, ald1, rowptr, csr_src, nullptr, zb);
    gemm_mfma<true, true><<<dim3(H1 / 64, mtiles), blk, 0, stream>>>(
        zb, w1t, y1, b1, N_NODES, F_IN, H1);

    // --- layer 2 (aggregate in output space) ---
    gemm_mfma<false, true><<<dim3(H2 / 64, mtiles), blk, 0, stream>>>(
        y1, w2t, h2, nullptr, N_NODES, H1, H2);
    gemv2_kernel<H1, true><<<nodeblocks, blk, 0, stream>>>(y1, wab + 256, wab + 768, als2, ald2);
    agg_kernel<H2, true, true, false, true, true><<<nodeblocks, blk, 0, stream>>>(
        h2, als2, ald2, rowptr, csr_src, b2, y2);

    // --- layer 3 (fp32 h, fused log_softmax) ---
    gemm_mfma<false, false><<<dim3(1, mtiles), blk, 0, stream>>>(
        y2, w3t, h3, nullptr, N_NODES, H2, N_CLS);
    gemv2_kernel<H2, true><<<nodeblocks, blk, 0, stream>>>(y2, wab + 1280, wab + 1536, als3, ald3);
    agg_kernel<N_CLS, true, false, true, false, false><<<nodeblocks, blk, 0, stream>>>(
        h3, als3, ald3, rowptr, csr_src, b3, out);
}

// Round 7
// 262.370 us; speedup vs baseline: 1.3624x; 1.0592x over previous
//
#include <hip/hip_runtime.h>
#include <math.h>

#define N_NODES 20000
#define N_EDGESC 320000
#define ET (N_EDGESC + N_NODES)   // 340000 incl. self-loops
#define F_IN 128
#define H1 512
#define H2 256
#define N_CLS 40
#define NEG_SLOPE 0.2f

typedef __attribute__((ext_vector_type(8))) short short8;
typedef __attribute__((ext_vector_type(4))) float floatx4;

__device__ __forceinline__ unsigned short f2bf(float x) {
    unsigned u = __float_as_uint(x);
    unsigned r = (u + 0x7fffu + ((u >> 16) & 1u)) >> 16;  // RNE
    return (unsigned short)r;
}
__device__ __forceinline__ float bflo(unsigned v) { return __uint_as_float(v << 16); }
__device__ __forceinline__ float bfhi(unsigned v) { return __uint_as_float(v & 0xffff0000u); }
__device__ __forceinline__ float leaky(float e) { return (e > 0.f) ? e : e * NEG_SLOPE; }

// ---------------- shared gemv body: als[i]=in[i,:].wvs, ald[i]=in[i,:].wvd --
template <int DIN, bool IN_BF16>
__device__ __forceinline__ void gemv2_body(int node, int lane, const void* __restrict__ in,
                                           const float* __restrict__ wvs,
                                           const float* __restrict__ wvd,
                                           float* __restrict__ als, float* __restrict__ ald) {
    constexpr int C = DIN / 64;
    float ss = 0.f, sd = 0.f;
    if constexpr (IN_BF16) {
        const unsigned short* r = (const unsigned short*)in + (size_t)node * DIN + lane * C;
        float f[C];
        if constexpr (C == 8) {
            uint4 v = *(const uint4*)r;
            f[0] = bflo(v.x); f[1] = bfhi(v.x); f[2] = bflo(v.y); f[3] = bfhi(v.y);
            f[4] = bflo(v.z); f[5] = bfhi(v.z); f[6] = bflo(v.w); f[7] = bfhi(v.w);
        } else {
            uint2 v = *(const uint2*)r;
            f[0] = bflo(v.x); f[1] = bfhi(v.x); f[2] = bflo(v.y); f[3] = bfhi(v.y);
        }
        #pragma unroll
        for (int c = 0; c < C; ++c) {
            ss += f[c] * wvs[lane * C + c];
            sd += f[c] * wvd[lane * C + c];
        }
    } else {
        const float* r = (const float*)in + (size_t)node * DIN + lane * 2;
        float2 v = *(const float2*)r;
        ss = v.x * wvs[lane * 2] + v.y * wvs[lane * 2 + 1];
        sd = v.x * wvd[lane * 2] + v.y * wvd[lane * 2 + 1];
    }
    #pragma unroll
    for (int off = 32; off; off >>= 1) {
        ss += __shfl_xor(ss, off);
        sd += __shfl_xor(sd, off);
    }
    if (lane == 0) { als[node] = ss; ald[node] = sd; }
}

// ---------------- prep: cast x, cast W^T x3, wa GEMVs, zero deg ------------
#define NCT (F_IN * H1 + H1 * H2 + H2 * N_CLS)  // 206848
#define PB_CASTX 2500                            // 20000*128/4/256
#define PB_CASTT ((NCT + 255) / 256)             // 808
#define PB_WA 224                                // (128+512+256)/4
#define PB_ZERO ((N_NODES + 255) / 256)          // 79

__global__ __launch_bounds__(256) void prep_kernel(
        const float* __restrict__ x, unsigned short* __restrict__ xb,
        const float* __restrict__ W1, unsigned short* __restrict__ w1t,
        const float* __restrict__ a1s, const float* __restrict__ a1d,
        const float* __restrict__ W2, unsigned short* __restrict__ w2t,
        const float* __restrict__ a2s, const float* __restrict__ a2d,
        const float* __restrict__ W3, unsigned short* __restrict__ w3t,
        const float* __restrict__ a3s, const float* __restrict__ a3d,
        float* __restrict__ wab, int* __restrict__ deg) {
    int bid = blockIdx.x, t = threadIdx.x;
    if (bid < PB_CASTX) {
        int i = (bid * 256 + t) * 4;
        float4 v = *(const float4*)(x + i);
        ushort4 o = { f2bf(v.x), f2bf(v.y), f2bf(v.z), f2bf(v.w) };
        *(ushort4*)(xb + i) = o;
    } else if (bid < PB_CASTX + PB_CASTT) {
        int i = (bid - PB_CASTX) * 256 + t;
        if (i < F_IN * H1) {
            int k = i >> 9, n = i & 511;
            w1t[n * F_IN + k] = f2bf(W1[i]);
        } else if (i < F_IN * H1 + H1 * H2) {
            int j = i - F_IN * H1;
            int k = j >> 8, n = j & 255;
            w2t[n * H1 + k] = f2bf(W2[j]);
        } else if (i < NCT) {
            int j = i - (F_IN * H1 + H1 * H2);
            int k = j / N_CLS, n = j - k * N_CLS;
            w3t[n * H2 + k] = f2bf(W3[j]);
        }
    } else if (bid < PB_CASTX + PB_CASTT + PB_WA) {
        int lane = t & 63;
        int row = (bid - PB_CASTX - PB_CASTT) * 4 + (t >> 6);  // 0..895
        const float *W, *vs, *vd;
        float *os, *od;
        int N, k;
        if (row < 128)      { k = row;       W = W1; vs = a1s; vd = a1d; os = wab;        od = wab + 128;  N = H1; }
        else if (row < 640) { k = row - 128; W = W2; vs = a2s; vd = a2d; os = wab + 256;  od = wab + 768;  N = H2; }
        else                { k = row - 640; W = W3; vs = a3s; vd = a3d; os = wab + 1280; od = wab + 1536; N = N_CLS; }
        const float* r = W + (size_t)k * N;
        float ss = 0.f, sd = 0.f;
        for (int n = lane; n < N; n += 64) {
            float v = r[n];
            ss += v * vs[n];
            sd += v * vd[n];
        }
        #pragma unroll
        for (int off = 32; off; off >>= 1) {
            ss += __shfl_xor(ss, off);
            sd += __shfl_xor(sd, off);
        }
        if (lane == 0) { os[k] = ss; od[k] = sd; }
    } else {
        int i = (bid - PB_CASTX - PB_CASTT - PB_WA) * 256 + t;
        if (i < N_NODES) deg[i] = 0;
    }
}

// ---------------- count_deg + gemv-L1 (fused, independent parts) ------------
#define CB_CNT ((ET + 255) / 256)  // 1329

__global__ __launch_bounds__(256) void count_gemv1_kernel(
        const int* __restrict__ ei, int* __restrict__ deg,
        const float* __restrict__ x, const float* __restrict__ wab,
        float* __restrict__ als1, float* __restrict__ ald1) {
    int bid = blockIdx.x, t = threadIdx.x;
    if (bid < CB_CNT) {
        int e = bid * 256 + t;
        if (e < ET) {
            int d = (e < N_EDGESC) ? ei[N_EDGESC + e] : (e - N_EDGESC);
            atomicAdd(&deg[d], 1);
        }
    } else {
        int node = (bid - CB_CNT) * 4 + (t >> 6);
        if (node < N_NODES)
            gemv2_body<F_IN, false>(node, t & 63, x, wab, wab + 128, als1, ald1);
    }
}

__global__ __launch_bounds__(1024) void scan_kernel(const int* __restrict__ deg,
                                                    int* __restrict__ rowptr,
                                                    int* __restrict__ writeptr) {
    __shared__ int sums[1024];
    int t = threadIdx.x;
    const int per = (N_NODES + 1023) / 1024;  // 20
    int base = t * per;
    int local = 0;
    for (int i = 0; i < per; ++i) {
        int idx = base + i;
        if (idx < N_NODES) local += deg[idx];
    }
    sums[t] = local;
    __syncthreads();
    for (int off = 1; off < 1024; off <<= 1) {
        int add = (t >= off) ? sums[t - off] : 0;
        __syncthreads();
        sums[t] += add;
        __syncthreads();
    }
    int run = sums[t] - local;
    for (int i = 0; i < per; ++i) {
        int idx = base + i;
        if (idx < N_NODES) {
            rowptr[idx] = run;
            writeptr[idx] = run;
            run += deg[idx];
        }
    }
    if (t == 1023) rowptr[N_NODES] = sums[1023];
}

__global__ void fill_kernel(const int* __restrict__ ei, int* __restrict__ writeptr,
                            int* __restrict__ csr_src) {
    int e = blockIdx.x * blockDim.x + threadIdx.x;
    if (e >= ET) return;
    int s, d;
    if (e < N_EDGESC) { s = ei[e]; d = ei[N_EDGESC + e]; }
    else { s = d = e - N_EDGESC; }
    int pos = atomicAdd(&writeptr[d], 1);
    csr_src[pos] = s;
}

// ---------------- MFMA GEMM (flattened 1D grid) + optional fused gemv ------
// C(MxN) = A(MxK bf16 rm) * Bt(NxK bf16 rm). MT: m-tile (128/64), NT: n-tiles.
// Blocks >= gemm_blocks run the gemv over gin (GDIN>0).
#define LDT 40   // padded LDS stride (bf16) per 32-wide k tile
#define LSO 66   // epilogue repack stride (bf16)

template <int MT, int NT, bool BIASRELU, bool OUT_BF16, int GDIN, bool GBF16>
__global__ __launch_bounds__(256) void gemm_fused(
        const unsigned short* __restrict__ A, const unsigned short* __restrict__ Bt,
        void* __restrict__ Cp, const float* __restrict__ bias,
        int M, int K, int N, int gemm_blocks,
        const void* __restrict__ gin, const float* __restrict__ wvs,
        const float* __restrict__ wvd, float* __restrict__ als, float* __restrict__ ald) {
    constexpr int MI = MT / 64;
    __shared__ unsigned short As[MT * LDT];
    __shared__ unsigned short Bs[64 * LDT];
    __shared__ unsigned short Ls[64 * LSO];
    int bid = blockIdx.x, t = threadIdx.x;
    int w = t >> 6, lane = t & 63;

    if (bid >= gemm_blocks) {
        if constexpr (GDIN > 0) {
            int node = (bid - gemm_blocks) * 4 + w;
            if (node < N_NODES)
                gemv2_body<GDIN, GBF16>(node, lane, gin, wvs, wvd, als, ald);
        }
        return;
    }

    int quad = lane >> 4, l16 = lane & 15;
    int bm = (bid / NT) * MT, bn = (bid % NT) * 64;

    int ar0 = t >> 2;
    int ak = (t & 3) * 8;

    floatx4 acc[MI][4];
    #pragma unroll
    for (int i = 0; i < MI; ++i)
        #pragma unroll
        for (int j = 0; j < 4; ++j) acc[i][j] = (floatx4){0.f, 0.f, 0.f, 0.f};

    uint4 pa0 = {0,0,0,0}, pa1 = {0,0,0,0}, pb = {0,0,0,0};
    {
        int gm0 = bm + ar0, gn = bn + ar0;
        if (gm0 < M) pa0 = *(const uint4*)(A + (size_t)gm0 * K + ak);
        if constexpr (MI == 2) {
            int gm1 = bm + 64 + ar0;
            if (gm1 < M) pa1 = *(const uint4*)(A + (size_t)gm1 * K + ak);
        }
        if (gn < N) pb = *(const uint4*)(Bt + (size_t)gn * K + ak);
    }

    for (int k0 = 0; k0 < K; k0 += 32) {
        *(uint4*)(&As[ar0 * LDT + ak]) = pa0;
        if constexpr (MI == 2) *(uint4*)(&As[(64 + ar0) * LDT + ak]) = pa1;
        *(uint4*)(&Bs[ar0 * LDT + ak]) = pb;
        __syncthreads();

        int kn = k0 + 32;
        if (kn < K) {
            int gm0 = bm + ar0, gn = bn + ar0;
            pa0 = (gm0 < M) ? *(const uint4*)(A + (size_t)gm0 * K + kn + ak) : (uint4){0,0,0,0};
            if constexpr (MI == 2) {
                int gm1 = bm + 64 + ar0;
                pa1 = (gm1 < M) ? *(const uint4*)(A + (size_t)gm1 * K + kn + ak) : (uint4){0,0,0,0};
            }
            pb = (gn < N) ? *(const uint4*)(Bt + (size_t)gn * K + kn + ak) : (uint4){0,0,0,0};
        }

        short8 a[MI], b[4];
        #pragma unroll
        for (int mi = 0; mi < MI; ++mi)
            a[mi] = *(short8*)(&As[(w * (MT / 4) + mi * 16 + l16) * LDT + quad * 8]);
        #pragma unroll
        for (int ni = 0; ni < 4; ++ni)
            b[ni] = *(short8*)(&Bs[(ni * 16 + l16) * LDT + quad * 8]);
        #pragma unroll
        for (int mi = 0; mi < MI; ++mi)
            #pragma unroll
            for (int ni = 0; ni < 4; ++ni)
                acc[mi][ni] = __builtin_amdgcn_mfma_f32_16x16x32_bf16(a[mi], b[ni], acc[mi][ni], 0, 0, 0);
        __syncthreads();
    }

    if constexpr (OUT_BF16) {
        #pragma unroll
        for (int mi = 0; mi < MI; ++mi) {
            #pragma unroll
            for (int ni = 0; ni < 4; ++ni) {
                int col = bn + ni * 16 + l16;
                #pragma unroll
                for (int r = 0; r < 4; ++r) {
                    float v = acc[mi][ni][r];
                    if constexpr (BIASRELU) v = fmaxf(v + bias[col], 0.f);
                    Ls[(w * 16 + quad * 4 + r) * LSO + ni * 16 + l16] = f2bf(v);
                }
            }
            __syncthreads();
            #pragma unroll
            for (int i = 0; i < 2; ++i) {
                int idx = t + i * 256;
                int lrow = idx >> 3, c8 = (idx & 7) * 8;
                int grow = bm + (lrow >> 4) * (MT / 4) + mi * 16 + (lrow & 15);
                if (grow < M)
                    *(uint4*)((unsigned short*)Cp + (size_t)grow * N + bn + c8) =
                        *(uint4*)(&Ls[lrow * LSO + c8]);
            }
            __syncthreads();
        }
    } else {
        #pragma unroll
        for (int mi = 0; mi < MI; ++mi) {
            #pragma unroll
            for (int r = 0; r < 4; ++r) {
                int row = bm + w * (MT / 4) + mi * 16 + quad * 4 + r;
                if (row >= M) continue;
                #pragma unroll
                for (int ni = 0; ni < 4; ++ni) {
                    int col = bn + ni * 16 + l16;
                    if (col < N) ((float*)Cp)[(size_t)row * N + col] = acc[mi][ni][r];
                }
            }
        }
    }
}

// ---------------- softmax-attention aggregation ----------------
template <int DOUT, bool BIAS, bool RELU, bool LSM, bool IN_BF16, bool OUT_BF16>
__global__ __launch_bounds__(256) void agg_kernel(const void* __restrict__ h,
                                                  const float* __restrict__ as,
                                                  const float* __restrict__ ad,
                                                  const int* __restrict__ rowptr,
                                                  const int* __restrict__ csr_src,
                                                  const float* __restrict__ bias,
                                                  void* __restrict__ outp) {
    constexpr int C = (DOUT + 63) / 64;
    int wave = threadIdx.x >> 6, lane = threadIdx.x & 63;
    int node = blockIdx.x * 4 + wave;
    if (node >= N_NODES) return;
    int beg = rowptr[node], end = rowptr[node + 1];
    float adi = ad[node];

    int k0 = beg + lane;
    bool has0 = k0 < end;
    int sj = has0 ? csr_src[k0] : 0;
    float ej = -INFINITY;
    if (has0) ej = leaky(as[sj] + adi);

    float m = ej;
    for (int k = k0 + 64; k < end; k += 64) m = fmaxf(m, leaky(as[csr_src[k]] + adi));
    #pragma unroll
    for (int off = 32; off; off >>= 1) m = fmaxf(m, __shfl_xor(m, off));

    float den = has0 ? expf(ej - m) : 0.f;
    for (int k = k0 + 64; k < end; k += 64) den += expf(leaky(as[csr_src[k]] + adi) - m);
    #pragma unroll
    for (int off = 32; off; off >>= 1) den += __shfl_xor(den, off);
    float invden = 1.f / den;

    float wgt = has0 ? expf(ej - m) * invden : 0.f;

    float acc[C];
    #pragma unroll
    for (int c = 0; c < C; ++c) acc[c] = 0.f;

    auto fetch = [&](int s, float* f) {
        if constexpr (IN_BF16) {
            const unsigned short* hr = (const unsigned short*)h + (size_t)s * DOUT + lane * C;
            if constexpr (C == 8) {
                uint4 v = *(const uint4*)hr;
                f[0] = bflo(v.x); f[1] = bfhi(v.x); f[2] = bflo(v.y); f[3] = bfhi(v.y);
                f[4] = bflo(v.z); f[5] = bfhi(v.z); f[6] = bflo(v.w); f[7] = bfhi(v.w);
            } else if constexpr (C == 4) {
                uint2 v = *(const uint2*)hr;
                f[0] = bflo(v.x); f[1] = bfhi(v.x); f[2] = bflo(v.y); f[3] = bfhi(v.y);
            } else {
                unsigned v = *(const unsigned*)hr;
                f[0] = bflo(v); f[1] = bfhi(v);
            }
        } else {
            if (lane < DOUT) f[0] = ((const float*)h)[(size_t)s * DOUT + lane];
            else f[0] = 0.f;
        }
    };

    int cnt0 = min(64, end - beg);
    int j = 0;
    for (; j + 7 < cnt0; j += 8) {
        int s[8]; float a[8]; float f[8][C];
        #pragma unroll
        for (int u = 0; u < 8; ++u) { s[u] = __shfl(sj, j + u); a[u] = __shfl(wgt, j + u); }
        #pragma unroll
        for (int u = 0; u < 8; ++u) fetch(s[u], f[u]);
        #pragma unroll
        for (int u = 0; u < 8; ++u)
            #pragma unroll
            for (int c = 0; c < C; ++c) acc[c] += a[u] * f[u][c];
    }
    for (; j < cnt0; ++j) {
        int s0 = __shfl(sj, j);
        float a0 = __shfl(wgt, j);
        float f0[C];
        fetch(s0, f0);
        #pragma unroll
        for (int c = 0; c < C; ++c) acc[c] += a0 * f0[c];
    }
    for (int base = beg + 64; base < end; base += 64) {  // rare: degree > 64
        int cnt = min(64, end - base);
        int sx = 0; float wx = 0.f;
        if (lane < cnt) {
            sx = csr_src[base + lane];
            wx = expf(leaky(as[sx] + adi) - m) * invden;
        }
        for (int jj = 0; jj < cnt; ++jj) {
            int s0 = __shfl(sx, jj);
            float a0 = __shfl(wx, jj);
            float f0[C];
            fetch(s0, f0);
            #pragma unroll
            for (int c = 0; c < C; ++c) acc[c] += a0 * f0[c];
        }
    }

    if constexpr (!LSM) {
        #pragma unroll
        for (int c = 0; c < C; ++c) {
            int col = lane * C + c;
            if (DOUT % 64 == 0 || col < DOUT) {
                float v = acc[c];
                if constexpr (BIAS) v += bias[col];
                if constexpr (RELU) v = fmaxf(v, 0.f);
                if constexpr (OUT_BF16)
                    ((unsigned short*)outp)[(size_t)node * DOUT + col] = f2bf(v);
                else
                    ((float*)outp)[(size_t)node * DOUT + col] = v;
            }
        }
    } else {
        float v = (lane < DOUT) ? (acc[0] + bias[lane]) : -INFINITY;
        float mm = v;
        #pragma unroll
        for (int off = 32; off; off >>= 1) mm = fmaxf(mm, __shfl_xor(mm, off));
        float ex = (lane < DOUT) ? expf(v - mm) : 0.f;
        float Z = ex;
        #pragma unroll
        for (int off = 32; off; off >>= 1) Z += __shfl_xor(Z, off);
        if (lane < DOUT) ((float*)outp)[(size_t)node * DOUT + lane] = v - mm - logf(Z);
    }
}

// ---------------- launch ----------------

extern "C" void kernel_launch(void* const* d_in, const int* in_sizes, int n_in,
                              void* d_out, int out_size, void* d_ws, size_t ws_size,
                              hipStream_t stream) {
    const float* x   = (const float*)d_in[0];
    const int*   ei  = (const int*)d_in[1];
    const float* W1  = (const float*)d_in[2];
    const float* a1s = (const float*)d_in[3];
    const float* a1d = (const float*)d_in[4];
    const float* b1  = (const float*)d_in[5];
    const float* W2  = (const float*)d_in[6];
    const float* a2s = (const float*)d_in[7];
    const float* a2d = (const float*)d_in[8];
    const float* b2  = (const float*)d_in[9];
    const float* W3  = (const float*)d_in[10];
    const float* a3s = (const float*)d_in[11];
    const float* a3d = (const float*)d_in[12];
    const float* b3  = (const float*)d_in[13];
    float* out = (float*)d_out;

    char* ws = (char*)d_ws;
    size_t off = 0;
    auto alloc = [&](size_t bytes) {
        void* p = ws + off;
        off = (off + bytes + 255) & ~(size_t)255;
        return p;
    };
    int*            deg      = (int*)alloc(N_NODES * 4);
    int*            writeptr = (int*)alloc(N_NODES * 4);
    int*            rowptr   = (int*)alloc((N_NODES + 1) * 4);
    int*            csr_src  = (int*)alloc((size_t)ET * 4);
    float*          alph     = (float*)alloc((size_t)6 * N_NODES * 4);
    float*          wab      = (float*)alloc(1792 * 4);
    unsigned short* xb       = (unsigned short*)alloc((size_t)N_NODES * F_IN * 2);
    unsigned short* w1t      = (unsigned short*)alloc((size_t)H1 * F_IN * 2);
    unsigned short* w2t      = (unsigned short*)alloc((size_t)H2 * H1 * 2);
    unsigned short* w3t      = (unsigned short*)alloc((size_t)N_CLS * H2 * 2);
    unsigned short* zb       = (unsigned short*)alloc((size_t)N_NODES * F_IN * 2);  // agg(x)
    unsigned short* y1       = (unsigned short*)alloc((size_t)N_NODES * H1 * 2);    // L1 out / L2-agg out (aliased)
    unsigned short* h2       = (unsigned short*)alloc((size_t)N_NODES * H2 * 2);
    float*          h3       = (float*)alloc((size_t)N_NODES * N_CLS * 4);
    (void)alloc(128 * 1024);  // slack

    unsigned short* y2 = y1;  // y1 fully consumed before y2 is produced

    float* als1 = alph + 0 * N_NODES; float* ald1 = alph + 1 * N_NODES;
    float* als2 = alph + 2 * N_NODES; float* ald2 = alph + 3 * N_NODES;
    float* als3 = alph + 4 * N_NODES; float* ald3 = alph + 5 * N_NODES;

    dim3 blk(256);
    int nodeblocks = (N_NODES + 3) / 4;            // 5000
    const int mt128 = (N_NODES + 127) / 128;       // 157
    const int mt64  = (N_NODES + 63) / 64;         // 313

    // 1. prep: cast x, W^T casts, wa GEMVs, zero deg
    prep_kernel<<<PB_CASTX + PB_CASTT + PB_WA + PB_ZERO, blk, 0, stream>>>(
        x, xb, W1, w1t, a1s, a1d, W2, w2t, a2s, a2d, W3, w3t, a3s, a3d, wab, deg);
    // 2. count_deg + gemv-L1
    count_gemv1_kernel<<<CB_CNT + nodeblocks, blk, 0, stream>>>(ei, deg, x, wab, als1, ald1);
    // 3. scan
    scan_kernel<<<1, 1024, 0, stream>>>(deg, rowptr, writeptr);
    // 4. fill CSR
    fill_kernel<<<(ET + 255) / 256, blk, 0, stream>>>(ei, writeptr, csr_src);

    // 5. layer 1: aggregate in input space (128 cols)
    agg_kernel<F_IN, false, false, false, true, true><<<nodeblocks, blk, 0, stream>>>(
        xb, als1, ald1, rowptr, csr_src, nullptr, zb);
    // 6. layer-1 GEMM: y1 = relu(zb @ W1 + b1)
    gemm_fused<128, 8, true, true, 0, false><<<8 * mt128, blk, 0, stream>>>(
        zb, w1t, y1, b1, N_NODES, F_IN, H1, 8 * mt128,
        nullptr, nullptr, nullptr, nullptr, nullptr);
    // 7. layer-2 GEMM (h2 = y1 @ W2) + fused gemv-L2 (als2 from y1)
    gemm_fused<128, 4, false, true, H1, true><<<4 * mt128 + nodeblocks, blk, 0, stream>>>(
        y1, w2t, h2, nullptr, N_NODES, H1, H2, 4 * mt128,
        y1, wab + 256, wab + 768, als2, ald2);
    // 8. layer-2 aggregation: y2 = relu(agg(h2) + b2)
    agg_kernel<H2, true, true, false, true, true><<<nodeblocks, blk, 0, stream>>>(
        h2, als2, ald2, rowptr, csr_src, b2, y2);
    // 9. layer-3 GEMM (h3 = y2 @ W3, fp32, MT=64) + fused gemv-L3 (als3 from y2)
    gemm_fused<64, 1, false, false, H2, true><<<mt64 + nodeblocks, blk, 0, stream>>>(
        y2, w3t, h3, nullptr, N_NODES, H2, N_CLS, mt64,
        y2, wab + 1280, wab + 1536, als3, ald3);
    // 10. layer-3 aggregation + bias + log_softmax
    agg_kernel<N_CLS, true, false, true, false, false><<<nodeblocks, blk, 0, stream>>>(
        h3, als3, ald3, rowptr, csr_src, b3, out);
}